// Round 2
// baseline (378.379 us; speedup 1.0000x reference)
//
#include <hip/hip_runtime.h>
#include <stdint.h>

// HMPNN layer: two NNConv(sum-agg) + sigmoid, concat, Linear(32,32), sigmoid.
// Reassociation: agg[d,o] = sum_f attr[e,f]*y[src_e,f,o], with
// y[n,f,o] = sum_i x_src[n,i]*w_msg[f,i,o] precomputed per NODE (16x less work).
// y stored bf16 (absmax 0.0039 vs thr 0.0166 verified in R1).
// edge_msg R2: 8 lanes/edge, 4x dwordx4 row fetch (0.75 wave-VMEM instr/edge
// vs 4.25 in R1), register-resident f-butterfly via shfl_xor.

#define NN 50000
#define EE 800000
#define YROW 272   // 17*16 bf16: f=0..15 attr rows + f=16 bias row

__device__ __forceinline__ float bf2f(unsigned short u) {
    union { unsigned int i; float f; } v; v.i = ((unsigned int)u) << 16; return v.f;
}
__device__ __forceinline__ unsigned short f2bf(float f) {
    union { float fl; unsigned int i; } v; v.fl = f;
    unsigned int x = v.i;
    x += 0x7FFFu + ((x >> 16) & 1u);   // round-to-nearest-even
    return (unsigned short)(x >> 16);
}
__device__ __forceinline__ float blo(unsigned int d) {
    union { unsigned int u; float f; } v; v.u = d << 16; return v.f;
}
__device__ __forceinline__ float bhi(unsigned int d) {
    union { unsigned int u; float f; } v; v.u = d & 0xFFFF0000u; return v.f;
}

// y[n, f*16+o] = sum_i x[n,i] * w_msg[f,i,o]  (f<16);  f==16 row: x[n,:]@b_msg
__global__ __launch_bounds__(256) void build_y(
    const float* __restrict__ x, const float* __restrict__ w_msg,
    const float* __restrict__ b_msg, unsigned short* __restrict__ y)
{
    __shared__ float sw[17 * 256];
    int tid = threadIdx.x;
    for (int idx = tid; idx < 17 * 256; idx += 256)
        sw[idx] = (idx < 4096) ? w_msg[idx] : b_msg[idx - 4096];
    __syncthreads();

    int n = blockIdx.x * 16 + (tid >> 4);
    if (n >= NN) return;
    int o = tid & 15;
    int lane = tid & 63;
    int gb = lane & ~15;

    float xv = x[n * 16 + o];
    float xi[16];
    #pragma unroll
    for (int i = 0; i < 16; ++i) xi[i] = __shfl(xv, gb + i);

    #pragma unroll
    for (int f = 0; f < 17; ++f) {
        float acc = 0.f;
        #pragma unroll
        for (int i = 0; i < 16; ++i)
            acc += xi[i] * sw[f * 256 + i * 16 + o];
        y[(size_t)n * YROW + f * 16 + o] = f2bf(acc);
    }
}

// 8 lanes per edge (32 edges/block). Lane l: h=l&1 (o-half), q=l>>1.
// Load k in 0..3: uint4 = y-row bytes [k*128+l*16, +16) = f=4k+q, o=8h+0..7.
__global__ __launch_bounds__(256) void edge_msg(
    const int* __restrict__ eidx, const float* __restrict__ attr,
    const unsigned short* __restrict__ y, float* __restrict__ agg)
{
    __shared__ float abuf[32][18];   // stride 18 words: breaks 4-way bank aliasing
    int tid = threadIdx.x;
    int slot = tid >> 3;             // 0..31 edges per block
    int l = tid & 7;
    int e = blockIdx.x * 32 + slot;  // grid exact: 800000/32 = 25000
    int h = l & 1, q = l >> 1;

    int src = eidx[e];
    int dst = eidx[EE + e];

    const uint4* row = (const uint4*)(y + (size_t)src * YROW);
    uint4 v0 = row[l];
    uint4 v1 = row[8 + l];
    uint4 v2 = row[16 + l];
    uint4 v3 = row[24 + l];
    uint4 vb = row[32 + h];          // bias row half for o=8h..8h+7
    float2 av = ((const float2*)(attr + (size_t)e * 16))[l];
    ((float2*)&abuf[slot][0])[l] = av;
    __syncthreads();

    float p[8];
    if (q == 0) {                    // bias counted once per (edge, h)
        p[0] = blo(vb.x); p[1] = bhi(vb.x); p[2] = blo(vb.y); p[3] = bhi(vb.y);
        p[4] = blo(vb.z); p[5] = bhi(vb.z); p[6] = blo(vb.w); p[7] = bhi(vb.w);
    } else {
        #pragma unroll
        for (int j = 0; j < 8; ++j) p[j] = 0.f;
    }

    float a0 = abuf[slot][q];        // attr[f=q]
    float a1 = abuf[slot][4 + q];
    float a2 = abuf[slot][8 + q];
    float a3 = abuf[slot][12 + q];

    p[0] += a0 * blo(v0.x); p[1] += a0 * bhi(v0.x); p[2] += a0 * blo(v0.y); p[3] += a0 * bhi(v0.y);
    p[4] += a0 * blo(v0.z); p[5] += a0 * bhi(v0.z); p[6] += a0 * blo(v0.w); p[7] += a0 * bhi(v0.w);
    p[0] += a1 * blo(v1.x); p[1] += a1 * bhi(v1.x); p[2] += a1 * blo(v1.y); p[3] += a1 * bhi(v1.y);
    p[4] += a1 * blo(v1.z); p[5] += a1 * bhi(v1.z); p[6] += a1 * blo(v1.w); p[7] += a1 * bhi(v1.w);
    p[0] += a2 * blo(v2.x); p[1] += a2 * bhi(v2.x); p[2] += a2 * blo(v2.y); p[3] += a2 * bhi(v2.y);
    p[4] += a2 * blo(v2.z); p[5] += a2 * bhi(v2.z); p[6] += a2 * blo(v2.w); p[7] += a2 * bhi(v2.w);
    p[0] += a3 * blo(v3.x); p[1] += a3 * bhi(v3.x); p[2] += a3 * blo(v3.y); p[3] += a3 * bhi(v3.y);
    p[4] += a3 * blo(v3.z); p[5] += a3 * bhi(v3.z); p[6] += a3 * blo(v3.w); p[7] += a3 * bhi(v3.w);

    // reduce over f-quarters: lanes {h, h+2, h+4, h+6} (xor on bits 1,2)
    #pragma unroll
    for (int j = 0; j < 8; ++j) p[j] += __shfl_xor(p[j], 2);
    #pragma unroll
    for (int j = 0; j < 8; ++j) p[j] += __shfl_xor(p[j], 4);

    // lane handles o = 8h+q and 8h+q+4: select p[q], p[q+4]
    float t0 = (q & 1) ? p[1] : p[0];
    float t1 = (q & 1) ? p[3] : p[2];
    float w1 = (q & 2) ? t1 : t0;
    float s0 = (q & 1) ? p[5] : p[4];
    float s1 = (q & 1) ? p[7] : p[6];
    float w2 = (q & 2) ? s1 : s0;

    int ob = dst * 16 + 8 * h + q;
    atomicAdd(&agg[ob], w1);
    atomicAdd(&agg[ob + 4], w2);
}

// out[n,d] = sigmoid( h @ w_lin + b_lin ), h = sigmoid(agg + x@root + bias)
__global__ __launch_bounds__(256) void finalize(
    const float* __restrict__ xind,
    const float* __restrict__ agg_a, const float* __restrict__ agg_b,
    const float* __restrict__ root_a, const float* __restrict__ bias_a,
    const float* __restrict__ root_b, const float* __restrict__ bias_b,
    const float* __restrict__ w_lin, const float* __restrict__ b_lin,
    float* __restrict__ out)
{
    int tid = threadIdx.x;
    int n = blockIdx.x * 8 + (tid >> 5);
    if (n >= NN) return;
    int d = tid & 31;
    int lane = tid & 63;
    int gb32 = lane & ~31;

    float xv = xind[n * 16 + (d & 15)];

    int j = d & 15;
    const float* root = (d < 16) ? root_a : root_b;
    const float* bias = (d < 16) ? bias_a : bias_b;
    const float* agg  = (d < 16) ? agg_a  : agg_b;

    float acc = agg[n * 16 + j] + bias[j];
    #pragma unroll
    for (int i = 0; i < 16; ++i) {
        float xiv = __shfl(xv, gb32 + i);
        acc += xiv * root[i * 16 + j];
    }
    float h = 1.f / (1.f + __expf(-acc));

    float acc2 = b_lin[d];
    #pragma unroll
    for (int jj = 0; jj < 32; ++jj) {
        float hj = __shfl(h, gb32 + jj);
        acc2 += hj * w_lin[jj * 32 + d];
    }
    out[(size_t)n * 32 + d] = 1.f / (1.f + __expf(-acc2));
}

extern "C" void kernel_launch(void* const* d_in, const int* in_sizes, int n_in,
                              void* d_out, int out_size, void* d_ws, size_t ws_size,
                              hipStream_t stream) {
    (void)in_sizes; (void)n_in; (void)out_size; (void)ws_size;
    const float* x_indivi = (const float*)d_in[0];
    const float* x_src_a  = (const float*)d_in[1];
    const float* x_src_b  = (const float*)d_in[2];
    const int*   ei_a     = (const int*)d_in[3];
    const int*   ei_b     = (const int*)d_in[4];
    const float* ea_a     = (const float*)d_in[5];
    const float* ea_b     = (const float*)d_in[6];
    const float* w_msg_a  = (const float*)d_in[7];
    const float* b_msg_a  = (const float*)d_in[8];
    const float* root_a   = (const float*)d_in[9];
    const float* bias_a   = (const float*)d_in[10];
    const float* w_msg_b  = (const float*)d_in[11];
    const float* b_msg_b  = (const float*)d_in[12];
    const float* root_b   = (const float*)d_in[13];
    const float* bias_b   = (const float*)d_in[14];
    const float* w_lin    = (const float*)d_in[15];
    const float* b_lin    = (const float*)d_in[16];
    float* out = (float*)d_out;

    char* ws = (char*)d_ws;
    size_t off = 0;
    // one shared y buffer: stream-serial build->use->rebuild (ws 60.8 -> 33.6 MB)
    unsigned short* ybuf = (unsigned short*)(ws + off); off += (size_t)NN * YROW * 2;
    float* agg_a = (float*)(ws + off); off += (size_t)NN * 16 * 4;
    float* agg_b = (float*)(ws + off); off += (size_t)NN * 16 * 4;

    hipMemsetAsync(agg_a, 0, (size_t)NN * 16 * 4 * 2, stream);

    build_y<<<(NN + 15) / 16, 256, 0, stream>>>(x_src_a, w_msg_a, b_msg_a, ybuf);
    edge_msg<<<EE / 32, 256, 0, stream>>>(ei_a, ea_a, ybuf, agg_a);

    build_y<<<(NN + 15) / 16, 256, 0, stream>>>(x_src_b, w_msg_b, b_msg_b, ybuf);
    edge_msg<<<EE / 32, 256, 0, stream>>>(ei_b, ea_b, ybuf, agg_b);

    finalize<<<(NN + 7) / 8, 256, 0, stream>>>(
        x_indivi, agg_a, agg_b, root_a, bias_a, root_b, bias_b, w_lin, b_lin, out);
}

// Round 3
// 304.347 us; speedup vs baseline: 1.2433x; 1.2433x over previous
//
#include <hip/hip_runtime.h>
#include <hip/hip_bf16.h>
#include <stdint.h>

// HMPNN layer: two NNConv(sum-agg)+sigmoid, concat, Linear(32,32), sigmoid.
// R3: z-outer-product formulation. msg[e,:] = z[e,:] @ W', where
//   z[e, f*16+i] = attr[e,f]*xj[e,i]  (k=0..255), z[e,256+i] = xj[e,i] (bias),
//   z[e,272..287] = 0 pad;  W'[288x16] fixed (w_msg reshaped + b_msg + zero pad).
// MFMA 16x16x32 bf16, 9 K-steps, 16 edges/wave. No y buffer, no random 544B
// gather (R1/R2's 242MB L2-miss wall), no build_y LDS-pipe kernel.

#define NN 50000
#define EE 800000

typedef __attribute__((ext_vector_type(8))) short short8;
typedef __attribute__((ext_vector_type(4))) float f32x4;

union U8 { short8 v; unsigned int u[4]; };

__device__ __forceinline__ unsigned short f2bf_rne(float f) {
    union { float fl; unsigned int i; } v; v.fl = f;
    unsigned int x = v.i;
    x += 0x7FFFu + ((x >> 16) & 1u);
    return (unsigned short)(x >> 16);
}

__device__ __forceinline__ unsigned int pack2bf(float a, float b) {
    __hip_bfloat162 h = __float22bfloat162_rn(float2{a, b}); // x=low, y=high
    union { __hip_bfloat162 h2; unsigned int u; } c; c.h2 = h;
    return c.u;
}

// Wfrag[t][lane][j] = bf16( W'[32t + (lane>>4)*8 + j][lane&15] ), t=0..8.
// Exact per-lane B-fragment order for mfma_f32_16x16x32_bf16 -> one dwordx4/lane/t.
__global__ void prep_w(const float* __restrict__ w_msg, const float* __restrict__ b_msg,
                       unsigned short* __restrict__ wfrag) {
    for (int idx = threadIdx.x; idx < 9 * 64 * 8; idx += 256) {
        int j = idx & 7;
        int lane = (idx >> 3) & 63;
        int t = idx >> 9;
        int k = 32 * t + (lane >> 4) * 8 + j;
        int n = lane & 15;
        int f = k >> 4, i = k & 15;
        float v = (f < 16) ? w_msg[f * 256 + i * 16 + n]
                           : (f == 16 ? b_msg[i * 16 + n] : 0.f);
        wfrag[idx] = f2bf_rne(v);
    }
}

// 16 edges per wave. Lane: m=lane&15 (edge in A / o-col in D), quad=lane>>4.
// A-frag t: element j = bf16( attr[m, 2t+(quad>>1)] * xj[m, (quad&1)*8+j] ).
// D: lane holds rows quad*4+r (edges), col m (o). Atomic pattern = contiguous
// 64B per edge (R1's 50MB WRITE_SIZE pattern, not R2's doubled one).
__global__ __launch_bounds__(256) void edge_mfma(
    const int* __restrict__ eidx, const float* __restrict__ attr,
    const float* __restrict__ x, const unsigned short* __restrict__ wfrag,
    float* __restrict__ agg)
{
    int lane = threadIdx.x & 63;
    int m = lane & 15, quad = lane >> 4;
    int q2 = quad >> 1, qb = quad & 1;
    int wave = (blockIdx.x * 256 + (int)threadIdx.x) >> 6;
    int nwaves = (gridDim.x * 256) >> 6;

    short8 bfr[9];
    #pragma unroll
    for (int t = 0; t < 9; ++t)
        bfr[t] = ((const short8*)wfrag)[t * 64 + lane];

    for (int g = wave; g < EE / 16; g += nwaves) {
        int ebase = g * 16;
        int src = eidx[ebase + m];
        int dstr[4];
        #pragma unroll
        for (int r = 0; r < 4; ++r)
            dstr[r] = eidx[EE + ebase + quad * 4 + r];

        const float4* xr = (const float4*)(x + (size_t)src * 16);
        float4 x0 = xr[qb * 2];        // xj[m, qb*8 + 0..3]
        float4 x1 = xr[qb * 2 + 1];    // xj[m, qb*8 + 4..7]
        float xh[8] = {x0.x, x0.y, x0.z, x0.w, x1.x, x1.y, x1.z, x1.w};

        const float* ar = attr + (size_t)(ebase + m) * 16;
        float ah[8];
        #pragma unroll
        for (int t = 0; t < 8; ++t) ah[t] = ar[2 * t + q2];

        f32x4 acc = {0.f, 0.f, 0.f, 0.f};
        #pragma unroll
        for (int t = 0; t < 8; ++t) {
            U8 a;
            #pragma unroll
            for (int jj = 0; jj < 4; ++jj)
                a.u[jj] = pack2bf(ah[t] * xh[2 * jj], ah[t] * xh[2 * jj + 1]);
            acc = __builtin_amdgcn_mfma_f32_16x16x32_bf16(a.v, bfr[t], acc, 0, 0, 0);
        }
        // t=8: k=256..287 -> bias row (q2==0: z=xj) / zero pad (q2==1)
        U8 a8;
        #pragma unroll
        for (int jj = 0; jj < 4; ++jj)
            a8.u[jj] = (q2 == 0) ? pack2bf(xh[2 * jj], xh[2 * jj + 1]) : 0u;
        acc = __builtin_amdgcn_mfma_f32_16x16x32_bf16(a8.v, bfr[8], acc, 0, 0, 0);

        #pragma unroll
        for (int r = 0; r < 4; ++r)
            atomicAdd(&agg[dstr[r] * 16 + m], acc[r]);
    }
}

// out[n,d] = sigmoid( h @ w_lin + b_lin ), h = sigmoid(agg + x@root + bias)
__global__ __launch_bounds__(256) void finalize(
    const float* __restrict__ xind,
    const float* __restrict__ agg_a, const float* __restrict__ agg_b,
    const float* __restrict__ root_a, const float* __restrict__ bias_a,
    const float* __restrict__ root_b, const float* __restrict__ bias_b,
    const float* __restrict__ w_lin, const float* __restrict__ b_lin,
    float* __restrict__ out)
{
    int tid = threadIdx.x;
    int n = blockIdx.x * 8 + (tid >> 5);
    if (n >= NN) return;
    int d = tid & 31;
    int lane = tid & 63;
    int gb32 = lane & ~31;

    float xv = xind[n * 16 + (d & 15)];

    int j = d & 15;
    const float* root = (d < 16) ? root_a : root_b;
    const float* bias = (d < 16) ? bias_a : bias_b;
    const float* agg  = (d < 16) ? agg_a  : agg_b;

    float acc = agg[n * 16 + j] + bias[j];
    #pragma unroll
    for (int i = 0; i < 16; ++i) {
        float xiv = __shfl(xv, gb32 + i);
        acc += xiv * root[i * 16 + j];
    }
    float h = 1.f / (1.f + __expf(-acc));

    float acc2 = b_lin[d];
    #pragma unroll
    for (int jj = 0; jj < 32; ++jj) {
        float hj = __shfl(h, gb32 + jj);
        acc2 += hj * w_lin[jj * 32 + d];
    }
    out[(size_t)n * 32 + d] = 1.f / (1.f + __expf(-acc2));
}

extern "C" void kernel_launch(void* const* d_in, const int* in_sizes, int n_in,
                              void* d_out, int out_size, void* d_ws, size_t ws_size,
                              hipStream_t stream) {
    (void)in_sizes; (void)n_in; (void)out_size; (void)ws_size;
    const float* x_indivi = (const float*)d_in[0];
    const float* x_src_a  = (const float*)d_in[1];
    const float* x_src_b  = (const float*)d_in[2];
    const int*   ei_a     = (const int*)d_in[3];
    const int*   ei_b     = (const int*)d_in[4];
    const float* ea_a     = (const float*)d_in[5];
    const float* ea_b     = (const float*)d_in[6];
    const float* w_msg_a  = (const float*)d_in[7];
    const float* b_msg_a  = (const float*)d_in[8];
    const float* root_a   = (const float*)d_in[9];
    const float* bias_a   = (const float*)d_in[10];
    const float* w_msg_b  = (const float*)d_in[11];
    const float* b_msg_b  = (const float*)d_in[12];
    const float* root_b   = (const float*)d_in[13];
    const float* bias_b   = (const float*)d_in[14];
    const float* w_lin    = (const float*)d_in[15];
    const float* b_lin    = (const float*)d_in[16];
    float* out = (float*)d_out;

    char* ws = (char*)d_ws;
    size_t off = 0;
    unsigned short* wf_a = (unsigned short*)(ws + off); off += 9 * 64 * 8 * 2;  // 9216B
    unsigned short* wf_b = (unsigned short*)(ws + off); off += 9 * 64 * 8 * 2;
    float* agg_a = (float*)(ws + off); off += (size_t)NN * 16 * 4;              // 3.2MB
    float* agg_b = (float*)(ws + off); off += (size_t)NN * 16 * 4;

    hipMemsetAsync(agg_a, 0, (size_t)NN * 16 * 4 * 2, stream);
    prep_w<<<1, 256, 0, stream>>>(w_msg_a, b_msg_a, wf_a);
    prep_w<<<1, 256, 0, stream>>>(w_msg_b, b_msg_b, wf_b);

    edge_mfma<<<1024, 256, 0, stream>>>(ei_a, ea_a, x_src_a, wf_a, agg_a);
    edge_mfma<<<1024, 256, 0, stream>>>(ei_b, ea_b, x_src_b, wf_b, agg_b);

    finalize<<<(NN + 7) / 8, 256, 0, stream>>>(
        x_indivi, agg_a, agg_b, root_a, bias_a, root_b, bias_b, w_lin, b_lin, out);
}

// Round 4
// 292.505 us; speedup vs baseline: 1.2936x; 1.0405x over previous
//
#include <hip/hip_runtime.h>
#include <hip/hip_bf16.h>
#include <stdint.h>

// HMPNN layer: two NNConv(sum-agg)+sigmoid, concat, Linear(32,32), sigmoid.
// R3: z-outer-product: msg[e,:] = z[e,:] @ W', z = attr (x) xj outer product
//     (k=288), MFMA 16x16x32 bf16, 9 K-steps, 16 edges/wave. FETCH 49MB. ok.
// R4: fuse metasteps a+b into ONE edge dispatch (parity-interleaved blocks,
//     8192 waves = 8 waves/SIMD vs R3's 4) — R3 was latency-bound at 35% occ.

#define NN 50000
#define EE 800000

typedef __attribute__((ext_vector_type(8))) short short8;
typedef __attribute__((ext_vector_type(4))) float f32x4;

union U8 { short8 v; unsigned int u[4]; };

__device__ __forceinline__ unsigned short f2bf_rne(float f) {
    union { float fl; unsigned int i; } v; v.fl = f;
    unsigned int x = v.i;
    x += 0x7FFFu + ((x >> 16) & 1u);
    return (unsigned short)(x >> 16);
}

__device__ __forceinline__ unsigned int pack2bf(float a, float b) {
    __hip_bfloat162 h = __float22bfloat162_rn(float2{a, b}); // x=low, y=high
    union { __hip_bfloat162 h2; unsigned int u; } c; c.h2 = h;
    return c.u;
}

// Wfrag[t][lane][j] = bf16( W'[32t + (lane>>4)*8 + j][lane&15] ), t=0..8.
// block 0 -> metastep a, block 1 -> metastep b.
__global__ void prep_w(const float* __restrict__ w_msg_a, const float* __restrict__ b_msg_a,
                       unsigned short* __restrict__ wf_a,
                       const float* __restrict__ w_msg_b, const float* __restrict__ b_msg_b,
                       unsigned short* __restrict__ wf_b) {
    const float* w_msg = blockIdx.x ? w_msg_b : w_msg_a;
    const float* b_msg = blockIdx.x ? b_msg_b : b_msg_a;
    unsigned short* wfrag = blockIdx.x ? wf_b : wf_a;
    for (int idx = threadIdx.x; idx < 9 * 64 * 8; idx += 256) {
        int j = idx & 7;
        int lane = (idx >> 3) & 63;
        int t = idx >> 9;
        int k = 32 * t + (lane >> 4) * 8 + j;
        int n = lane & 15;
        int f = k >> 4, i = k & 15;
        float v = (f < 16) ? w_msg[f * 256 + i * 16 + n]
                           : (f == 16 ? b_msg[i * 16 + n] : 0.f);
        wfrag[idx] = f2bf_rne(v);
    }
}

// 16 edges per wave-iteration. Lane: m=lane&15 (edge row in A / o-col in D),
// quad=lane>>4. A-frag t elem j = bf16( attr[m, 2t+(quad>>1)] * xj[m,(quad&1)*8+j] ).
// Both metasteps in one dispatch: blockIdx parity selects the pointer set.
__global__ __launch_bounds__(256) void edge_mfma(
    const int* __restrict__ ei_a, const float* __restrict__ ea_a,
    const float* __restrict__ x_a, const unsigned short* __restrict__ wf_a,
    float* __restrict__ agg_a,
    const int* __restrict__ ei_b, const float* __restrict__ ea_b,
    const float* __restrict__ x_b, const unsigned short* __restrict__ wf_b,
    float* __restrict__ agg_b)
{
    int ms = blockIdx.x & 1;
    const int* __restrict__ eidx  = ms ? ei_b : ei_a;
    const float* __restrict__ attr = ms ? ea_b : ea_a;
    const float* __restrict__ x    = ms ? x_b : x_a;
    const unsigned short* __restrict__ wfrag = ms ? wf_b : wf_a;
    float* __restrict__ agg = ms ? agg_b : agg_a;

    int lane = threadIdx.x & 63;
    int m = lane & 15, quad = lane >> 4;
    int q2 = quad >> 1, qb = quad & 1;
    int wave = ((blockIdx.x >> 1) * 256 + (int)threadIdx.x) >> 6;
    int nwaves = (gridDim.x >> 1) * 4;

    short8 bfr[9];
    #pragma unroll
    for (int t = 0; t < 9; ++t)
        bfr[t] = ((const short8*)wfrag)[t * 64 + lane];

    for (int g = wave; g < EE / 16; g += nwaves) {
        int ebase = g * 16;
        int src = eidx[ebase + m];
        int dstr[4];
        #pragma unroll
        for (int r = 0; r < 4; ++r)
            dstr[r] = eidx[EE + ebase + quad * 4 + r];

        const float4* xr = (const float4*)(x + (size_t)src * 16);
        float4 x0 = xr[qb * 2];        // xj[m, qb*8 + 0..3]
        float4 x1 = xr[qb * 2 + 1];    // xj[m, qb*8 + 4..7]
        float xh[8] = {x0.x, x0.y, x0.z, x0.w, x1.x, x1.y, x1.z, x1.w};

        const float* ar = attr + (size_t)(ebase + m) * 16;
        float ah[8];
        #pragma unroll
        for (int t = 0; t < 8; ++t) ah[t] = ar[2 * t + q2];

        f32x4 acc = {0.f, 0.f, 0.f, 0.f};
        #pragma unroll
        for (int t = 0; t < 8; ++t) {
            U8 a;
            #pragma unroll
            for (int jj = 0; jj < 4; ++jj)
                a.u[jj] = pack2bf(ah[t] * xh[2 * jj], ah[t] * xh[2 * jj + 1]);
            acc = __builtin_amdgcn_mfma_f32_16x16x32_bf16(a.v, bfr[t], acc, 0, 0, 0);
        }
        // t=8: k=256..287 -> bias row (q2==0: z=xj) / zero pad (q2==1)
        U8 a8;
        #pragma unroll
        for (int jj = 0; jj < 4; ++jj)
            a8.u[jj] = (q2 == 0) ? pack2bf(xh[2 * jj], xh[2 * jj + 1]) : 0u;
        acc = __builtin_amdgcn_mfma_f32_16x16x32_bf16(a8.v, bfr[8], acc, 0, 0, 0);

        #pragma unroll
        for (int r = 0; r < 4; ++r)
            atomicAdd(&agg[dstr[r] * 16 + m], acc[r]);
    }
}

// out[n,d] = sigmoid( h @ w_lin + b_lin ), h = sigmoid(agg + x@root + bias)
__global__ __launch_bounds__(256) void finalize(
    const float* __restrict__ xind,
    const float* __restrict__ agg_a, const float* __restrict__ agg_b,
    const float* __restrict__ root_a, const float* __restrict__ bias_a,
    const float* __restrict__ root_b, const float* __restrict__ bias_b,
    const float* __restrict__ w_lin, const float* __restrict__ b_lin,
    float* __restrict__ out)
{
    int tid = threadIdx.x;
    int n = blockIdx.x * 8 + (tid >> 5);
    if (n >= NN) return;
    int d = tid & 31;
    int lane = tid & 63;
    int gb32 = lane & ~31;

    float xv = xind[n * 16 + (d & 15)];

    int j = d & 15;
    const float* root = (d < 16) ? root_a : root_b;
    const float* bias = (d < 16) ? bias_a : bias_b;
    const float* agg  = (d < 16) ? agg_a  : agg_b;

    float acc = agg[n * 16 + j] + bias[j];
    #pragma unroll
    for (int i = 0; i < 16; ++i) {
        float xiv = __shfl(xv, gb32 + i);
        acc += xiv * root[i * 16 + j];
    }
    float h = 1.f / (1.f + __expf(-acc));

    float acc2 = b_lin[d];
    #pragma unroll
    for (int jj = 0; jj < 32; ++jj) {
        float hj = __shfl(h, gb32 + jj);
        acc2 += hj * w_lin[jj * 32 + d];
    }
    out[(size_t)n * 32 + d] = 1.f / (1.f + __expf(-acc2));
}

extern "C" void kernel_launch(void* const* d_in, const int* in_sizes, int n_in,
                              void* d_out, int out_size, void* d_ws, size_t ws_size,
                              hipStream_t stream) {
    (void)in_sizes; (void)n_in; (void)out_size; (void)ws_size;
    const float* x_indivi = (const float*)d_in[0];
    const float* x_src_a  = (const float*)d_in[1];
    const float* x_src_b  = (const float*)d_in[2];
    const int*   ei_a     = (const int*)d_in[3];
    const int*   ei_b     = (const int*)d_in[4];
    const float* ea_a     = (const float*)d_in[5];
    const float* ea_b     = (const float*)d_in[6];
    const float* w_msg_a  = (const float*)d_in[7];
    const float* b_msg_a  = (const float*)d_in[8];
    const float* root_a   = (const float*)d_in[9];
    const float* bias_a   = (const float*)d_in[10];
    const float* w_msg_b  = (const float*)d_in[11];
    const float* b_msg_b  = (const float*)d_in[12];
    const float* root_b   = (const float*)d_in[13];
    const float* bias_b   = (const float*)d_in[14];
    const float* w_lin    = (const float*)d_in[15];
    const float* b_lin    = (const float*)d_in[16];
    float* out = (float*)d_out;

    char* ws = (char*)d_ws;
    size_t off = 0;
    unsigned short* wf_a = (unsigned short*)(ws + off); off += 9 * 64 * 8 * 2;  // 9216B
    unsigned short* wf_b = (unsigned short*)(ws + off); off += 9 * 64 * 8 * 2;
    float* agg_a = (float*)(ws + off); off += (size_t)NN * 16 * 4;              // 3.2MB
    float* agg_b = (float*)(ws + off); off += (size_t)NN * 16 * 4;

    hipMemsetAsync(agg_a, 0, (size_t)NN * 16 * 4 * 2, stream);
    prep_w<<<2, 256, 0, stream>>>(w_msg_a, b_msg_a, wf_a, w_msg_b, b_msg_b, wf_b);

    // 2048 blocks = 8192 waves = 8 waves/SIMD demand (VGPR 56 allows 8 resident)
    edge_mfma<<<2048, 256, 0, stream>>>(ei_a, ea_a, x_src_a, wf_a, agg_a,
                                        ei_b, ea_b, x_src_b, wf_b, agg_b);

    finalize<<<(NN + 7) / 8, 256, 0, stream>>>(
        x_indivi, agg_a, agg_b, root_a, bias_a, root_b, bias_b, w_lin, b_lin, out);
}